// Round 16
// baseline (258.090 us; speedup 1.0000x reference)
//
#include <hip/hip_runtime.h>
#include <math.h>

typedef short s16x8 __attribute__((ext_vector_type(8)));
typedef unsigned short u16x8v __attribute__((ext_vector_type(8)));
typedef float f32x4 __attribute__((ext_vector_type(4)));
typedef _Float16 h2 __attribute__((ext_vector_type(2)));

#define HH 28
#define WW 28
#define PP 784
#define CC 128
#define GG 64
#define MT 48     // macro-tile tokens (3 halves of 16)
#define NH 3
#define AST 136   // bf16 row stride for 128-ch buffers
#define GSTB 72   // bf16 row stride for 64-ch buffers

// ---- workspace layout (float-slot offsets); acc regions hold f16 ----
#define OFF_FMT0 0
#define OFF_FMT1 100352
#define OFF_FGT0 200704
#define OFF_FGT1 250880
#define OFF_ACCM0 301056
#define OFF_ACCM1 401408
#define OFF_ACCG0 501760
#define OFF_ACCG1 551936
#define OFF_ACCW0 602112
#define OFF_ACCW1 602896
#define ACC_FLOATS 302624   // accm0..accw1 (zeroing range; f32 zeros = f16 zero pairs)
#define OFF_CNT   603680    // 24 ints  (region*3+group)
#define OFF_CNT2  603704    // 24 ints
#define OFF_JOB   603728    // 1568 ints -> ends 605296
#define OFF_WB    605296    // bf16 weights, 393216 ushorts -> ends 801904

// bf16 weight sub-offsets (ushort units), layout [set=(si*2+d)][out][in]
#define WIB 0        // Wi^T
#define WZB 98304    // Wz^T
#define WDB 147456   // Wid = (Wi@Wdt)^T  (composite)
#define WOB 245760   // Wo^T
#define WYB 344064   // Wyg^T

struct KArgs {
  const float* fm[2]; const float* fg[2];
  const float* flow[2]; const float* sx[2]; const float* sy[2];
  const float* Wi; const float* Wz; const float* Wdt; const float* bdt;
  const float* alog; const float* Wo; const float* Wyg;
  float* fmT[2]; float* fgT[2];
  float* accm[2]; float* accg[2]; float* accw[2];   // accm/accg interpreted as f16
  int* cnt; int* cnt2; int* job;
  unsigned short* wb;
  float* out;
};

__device__ __forceinline__ int span_group(float avg, int& s) {
  if (fabsf(avg - 15.f) < 1.5f) { s = 15; return 0; }
  if (fabsf(avg - 9.f)  < 1.5f) { s = 9;  return 1; }
  if (fabsf(avg - 5.f)  < 1.5f) { s = 5;  return 2; }
  s = 0; return 3;
}

__device__ __forceinline__ float fast_silu(float x) {
  return x * __builtin_amdgcn_rcpf(1.f + __expf(-x));
}

__device__ __forceinline__ unsigned short f2bf(float f) {
  unsigned u = __float_as_uint(f);
  unsigned r = (u + 0x7fffu + ((u >> 16) & 1u)) >> 16;
  return (unsigned short)r;
}
__device__ __forceinline__ float b2f(unsigned short u) {
  return __uint_as_float(((unsigned)u) << 16);
}

// packed 2xf16 atomic add (HW global_atomic_pk_add_f16; CAS fallback)
__device__ __forceinline__ void atomic_pk2(_Float16* base, float x, float y) {
  h2 v; v[0] = (_Float16)x; v[1] = (_Float16)y;
#if __has_builtin(__builtin_amdgcn_global_atomic_fadd_v2f16)
  __builtin_amdgcn_global_atomic_fadd_v2f16((h2*)base, v);
#else
  unsigned* a = (unsigned*)base;
  unsigned old = *a, assumed;
  do {
    assumed = old;
    h2 cur = *(h2*)&assumed;
    h2 nw; nw[0] = cur[0] + v[0]; nw[1] = cur[1] + v[1];
    old = atomicCAS(a, assumed, *(unsigned*)&nw);
  } while (old != assumed);
#endif
}

#define MFMA(A_, B_, C_) __builtin_amdgcn_mfma_f32_16x16x32_bf16((A_), (B_), (C_), 0, 0, 0)

__global__ void k_zero(float* p, int n) {
  int j = blockIdx.x * 256 + threadIdx.x;
  if (j < n) p[j] = 0.f;
}

// transpose features to [pos][ch], f32
__global__ void k_prep(KArgs a) {
  int j = blockIdx.x * 256 + threadIdx.x;     // 301056 exactly
  int side = j / 150528; int r = j - side * 150528;
  int p = r / 192; int ch = r - p * 192;
  if (ch < CC) a.fmT[side][p * CC + ch] = a.fm[side][ch * PP + p];
  else         a.fgT[side][p * GG + (ch - CC)] = a.fg[side][(ch - CC) * PP + p];
}

// transpose + bf16-convert weights to [set][out][in]; WDB written by k_prepwid
__global__ void k_prepw(KArgs a) {
  int j = blockIdx.x * 256 + threadIdx.x;     // 393216 exactly
  unsigned short* wb = a.wb;
  if (j < 98304) {
    int set = j >> 14, r = j & 16383; int o = r >> 7, c = r & 127;
    wb[WIB + j] = f2bf(a.Wi[set * 16384 + c * 128 + o]);
  } else if (j < 147456) {
    int r = j - 98304; int set = r >> 13, rr = r & 8191; int o = rr >> 6, c = rr & 63;
    wb[WZB + r] = f2bf(a.Wz[set * 8192 + c * 128 + o]);
  } else if (j < 245760) {
    // WDB region: written by k_prepwid
  } else if (j < 344064) {
    int r = j - 245760; int set = r >> 14, rr = r & 16383; int o = rr >> 7, c = rr & 127;
    wb[WOB + r] = f2bf(a.Wo[set * 16384 + c * 128 + o]);
  } else {
    int r = j - 344064; int set = r >> 13, rr = r & 8191; int o = rr >> 7, c = rr & 127;
    wb[WYB + r] = f2bf(a.Wyg[set * 8192 + c * 64 + o]);
  }
}

// composite Wid[set][o][i] = sum_m Wi[set][i][m] * Wdt[set][m][o]
__global__ void k_prepwid(KArgs a) {
  __shared__ float wi_row[128];
  const int set = blockIdx.x, i = blockIdx.y, o = threadIdx.x;
  wi_row[o] = a.Wi[set * 16384 + i * 128 + o];
  __syncthreads();
  float acc = 0.f;
#pragma unroll 4
  for (int m = 0; m < 128; ++m) acc = fmaf(wi_row[m], a.Wdt[set * 16384 + m * 128 + o], acc);
  a.wb[WDB + set * 16384 + o * 128 + i] = f2bf(acc);
}

// per-(region,group) counts; also reset job slots to -1
__global__ void k_count(KArgs a) {
  int j = blockIdx.x * 256 + threadIdx.x;
  if (j >= 2 * PP) return;
  a.job[j] = -1;
  int side = j / PP, p = j - side * PP;
  float avg = 0.5f * (a.sx[side][p] + a.sy[side][p]);
  int s; int g = span_group(avg, s);
  if (g < 3) {
    int py = p / WW, px = p - py * WW;
    int region = (py / 14) * 4 + px / 7;
    atomicAdd(&a.cnt[region * 3 + g], 1);
  }
}

// XCD-clustered slots: slot = region + 8*rank; span-15 gets low ranks.
__global__ void k_assign(KArgs a) {
  int j = blockIdx.x * 256 + threadIdx.x;
  if (j >= 2 * PP) return;
  int side = j / PP, p = j - side * PP;
  float avg = 0.5f * (a.sx[side][p] + a.sy[side][p]);
  int s; int g = span_group(avg, s);
  if (g < 3) {
    int py = p / WW, px = p - py * WW;
    int region = (py / 14) * 4 + px / 7;
    int base = 0;
    for (int gg = 0; gg < g; ++gg) base += a.cnt[region * 3 + gg];
    int rank = base + atomicAdd(&a.cnt2[region * 3 + g], 1);
    a.job[region + 8 * rank] = (side << 10) | p;   // rank <= 195 -> slot <= 1567
  }
}

__global__ void k_fin(KArgs a) {
  int j = blockIdx.x * 256 + threadIdx.x;     // 301056 exactly
  int side = j / 150528; int r = j - side * 150528;
  int p = r / 192; int ch = r - p * 192;
  float inv = 1.f / fmaxf(a.accw[side][p], 1e-6f);
  if (ch < CC) {
    const _Float16* amh = (const _Float16*)a.accm[side];
    a.out[side * 100352 + ch * PP + p] = (float)amh[p * CC + ch] * inv;
  } else {
    const _Float16* agh = (const _Float16*)a.accg[side];
    a.out[200704 + side * 50176 + (ch - CC) * PP + p] = (float)agh[p * GG + (ch - CC)] * inv;
  }
}

__launch_bounds__(256, 3)
__global__ void k_main(KArgs a) {
  __shared__ __align__(16) unsigned short mres[MT * AST];   // bf16 m residual (single)
  __shared__ __align__(16) unsigned short gres[MT * GSTB];  // bf16 g residual (single)
  __shared__ __align__(16) unsigned short bufA[MT * AST];   // xnorm_m, then y
  __shared__ __align__(16) unsigned short bufB[MT * GSTB];  // gnorm
  __shared__ float hs[2 * CC];
  __shared__ float na_s[2 * CC];
  __shared__ float bb_s[2 * CC];
  __shared__ float pw_l[228];
  __shared__ int   tap_i[MT * 4];
  __shared__ float tap_w[MT * 4];
  __shared__ int   sc_i[2][MT];
  __shared__ float sc_w[2][MT];
  __shared__ float red[4];

  const int tid = threadIdx.x;
  const int job = a.job[blockIdx.x];
  if (job < 0) return;
  const int side = job >> 10, p = job & 1023;
  const float avg = 0.5f * (a.sx[side][p] + a.sy[side][p]);
  int s; const int si = span_group(avg, s);
  const int hspan = s >> 1, L = s * s;
  const int py = p / WW, px = p - py * WW;
  const float fdx = a.flow[side][p * 4 + 0], fdy = a.flow[side][p * 4 + 1];
  const float cy = fminf(fmaxf((float)py + fdy, 0.f), (float)(HH - 1));
  const float cx = fminf(fmaxf((float)px + fdx, 0.f), (float)(WW - 1));
  const float* fmT = a.fmT[side]; const float* fgT = a.fgT[side];
  _Float16* accm_h = (_Float16*)a.accm[side];
  _Float16* accg_h = (_Float16*)a.accg[side];
  float* accw = a.accw[side];

  const unsigned short* wb = a.wb;
  const int wv = tid >> 6, l = tid & 63, lm = l & 15, g = l >> 4;
  const int o0 = 32 * wv + lm, o1 = o0 + 16, og = 16 * wv + lm;
  const int ttk = tid >> 3, c8 = tid & 7;     // sampling decomposition (2 tokens/thread)

  { const int d2 = tid >> 7, c2 = tid & 127;
    na_s[tid] = -__expf(a.alog[(si * 2 + d2) * CC + c2]);
    bb_s[tid] = a.bdt[(si * 2 + d2) * CC + c2];
    hs[tid] = 0.f; }
  if (tid < L) {
    const int dyi = tid / s - hspan, dxi = tid % s - hspan;
    pw_l[tid] = __expf(-sqrtf((float)(dyi * dyi + dxi * dxi)) / (0.5f * (float)s));
  }
  __syncthreads();
  { float v = (tid < L) ? pw_l[tid] : 0.f;
#pragma unroll
    for (int off = 32; off > 0; off >>= 1) v += __shfl_xor(v, off);
    if ((tid & 63) == 0) red[tid >> 6] = v; }
  __syncthreads();
  { const float pinv = 1.f / (red[0] + red[1] + red[2] + red[3]);
    if (tid < L) pw_l[tid] *= pinv; }
  __syncthreads();

  // taps for tile starting at t0_ into tap arrays + sc[b_]; all MT slots written
  auto comp_taps = [&](int t0_, int b_) {
    if (tid < MT) {
      const int t = t0_ + tid;
      if (t < L) {
        const int tq = t / s;
        const int dyi = tq - hspan, dxi = (t - tq * s) - hspan;
        const float ys = cy + (float)dyi, xs = cx + (float)dxi;
        const float y0f = floorf(ys), x0f = floorf(xs);
        const float wy = ys - y0f, wx = xs - x0f;
        const int y0 = (int)y0f, x0 = (int)x0f;
#pragma unroll
        for (int k = 0; k < 4; ++k) {
          const int yi = y0 + (k >> 1), xi = x0 + (k & 1);
          const bool v = (yi >= 0) && (yi < HH) && (xi >= 0) && (xi < WW);
          const int yc = min(max(yi, 0), HH - 1), xc = min(max(xi, 0), WW - 1);
          tap_i[tid * 4 + k] = yc * WW + xc;
          const float wgt = ((k >> 1) ? wy : 1.f - wy) * ((k & 1) ? wx : 1.f - wx);
          tap_w[tid * 4 + k] = v ? wgt : 0.f;
        }
        const int ty = py + dyi, tx = px + dxi;
        const bool sv = (ty >= 0) && (ty < HH) && (tx >= 0) && (tx < WW);
        const int sid2 = sv ? ty * WW + tx : 0;
        const float sw = sv ? pw_l[t] : 0.f;
        sc_i[b_][tid] = sid2; sc_w[b_][tid] = sw;
        if (sw != 0.f) atomicAdd(&accw[sid2], sw);
      } else {
#pragma unroll
        for (int k = 0; k < 4; ++k) { tap_i[tid * 4 + k] = 0; tap_w[tid * 4 + k] = 0.f; }
        sc_i[b_][tid] = 0; sc_w[b_][tid] = 0.f;
      }
    }
  };

  // register-held gather: thread covers tokens {ttk, ttk+32} x 16 m-ch + 8 g-ch
  f32x4 smM[2][4], smG[2][2];
  auto gather_tile = [&]() {
#pragma unroll
    for (int q = 0; q < 2; ++q) {
      const int tk = ttk + 32 * q;
#pragma unroll
      for (int v = 0; v < 4; ++v) smM[q][v] = (f32x4){0.f,0.f,0.f,0.f};
#pragma unroll
      for (int v = 0; v < 2; ++v) smG[q][v] = (f32x4){0.f,0.f,0.f,0.f};
      if (tk < MT) {
        const int* ti = &tap_i[tk * 4]; const float* tw = &tap_w[tk * 4];
#pragma unroll
        for (int k2 = 0; k2 < 4; ++k2) {
          const float w = tw[k2];
          const float* pm = &fmT[ti[k2] * CC + c8 * 16];
#pragma unroll
          for (int v = 0; v < 4; ++v) smM[q][v] += w * *(const f32x4*)&pm[4 * v];
          const float* pg = &fgT[ti[k2] * GG + c8 * 8];
#pragma unroll
          for (int v = 0; v < 2; ++v) smG[q][v] += w * *(const f32x4*)&pg[4 * v];
        }
      }
    }
  };
  // write gathered registers into LDS residual tiles (same-thread rmsnorm reads)
  auto write_samples = [&]() {
#pragma unroll
    for (int q = 0; q < 2; ++q) {
      const int tk = ttk + 32 * q;
      if (tk < MT) {
        u16x8v w0, w1, wg;
#pragma unroll
        for (int j = 0; j < 4; ++j) {
          w0[j] = f2bf(smM[q][0][j]); w0[4 + j] = f2bf(smM[q][1][j]);
          w1[j] = f2bf(smM[q][2][j]); w1[4 + j] = f2bf(smM[q][3][j]);
          wg[j] = f2bf(smG[q][0][j]); wg[4 + j] = f2bf(smG[q][1][j]);
        }
        *(u16x8v*)&mres[tk * AST + c8 * 16] = w0;
        *(u16x8v*)&mres[tk * AST + c8 * 16 + 8] = w1;
        *(u16x8v*)&gres[tk * GSTB + c8 * 8] = wg;
      }
    }
  };

  const int nt = (L + MT - 1) / MT;
  comp_taps(0, 0);
  __syncthreads();
  gather_tile();
  int cur = 0;

  for (int t = 0; t < nt; ++t) {
    const int t0 = t * MT;
    const int tlen = min(MT, L - t0);
    const int nxt = cur ^ 1;
    __syncthreads();   // all mres/gres/tap readers of prev tile done
    write_samples();   // tile t samples regs -> LDS (same-thread rmsnorm reads)
    if (t + 1 < nt) comp_taps(t0 + MT, nxt);

    for (int d = 0; d < 2; ++d) {
      const unsigned short* Wib  = wb + WIB + (si * 2 + d) * 16384;
      const unsigned short* Widb = wb + WDB + (si * 2 + d) * 16384;
      const unsigned short* Wzb  = wb + WZB + (si * 2 + d) * 8192;
      const unsigned short* Wob  = wb + WOB + (si * 2 + d) * 16384;
      const unsigned short* Wyb  = wb + WYB + (si * 2 + d) * 8192;
      if (d == 1) __syncthreads();   // d0 residual updates visible
      // rmsnorm: thread covers tokens {ttk, ttk+32}, 8 lanes/token
      for (int tk = ttk; tk < MT; tk += 32) {
        u16x8v m0 = *(const u16x8v*)&mres[tk * AST + c8 * 16];
        u16x8v m1 = *(const u16x8v*)&mres[tk * AST + c8 * 16 + 8];
        u16x8v gv = *(const u16x8v*)&gres[tk * GSTB + c8 * 8];
        float mv[16], gvf[8];
#pragma unroll
        for (int k = 0; k < 8; ++k) { mv[k] = b2f(m0[k]); mv[8 + k] = b2f(m1[k]); gvf[k] = b2f(gv[k]); }
        float ssm = 0.f, ssg = 0.f;
#pragma unroll
        for (int k = 0; k < 16; ++k) ssm = fmaf(mv[k], mv[k], ssm);
#pragma unroll
        for (int k = 0; k < 8; ++k) ssg = fmaf(gvf[k], gvf[k], ssg);
#pragma unroll
        for (int off = 4; off > 0; off >>= 1) { ssm += __shfl_xor(ssm, off); ssg += __shfl_xor(ssg, off); }
        const float sm = rsqrtf(ssm * (1.f / CC) + 1e-5f);
        const float sgs = rsqrtf(ssg * (1.f / GG) + 1e-5f);
        u16x8v xa, xb, gx;
#pragma unroll
        for (int k = 0; k < 8; ++k) { xa[k] = f2bf(mv[k] * sm); xb[k] = f2bf(mv[8 + k] * sm); gx[k] = f2bf(gvf[k] * sgs); }
        *(u16x8v*)&bufA[tk * AST + c8 * 16] = xa;
        *(u16x8v*)&bufA[tk * AST + c8 * 16 + 8] = xb;
        *(u16x8v*)&bufB[tk * GSTB + c8 * 8] = gx;
      }
      __syncthreads();   // xnorm/gnorm (and taps) visible
      // u = x@Wi ; delta_pre = x@Wid ; z = silu(g@Wz)  (ss-outer B-frag reuse)
      f32x4 u[NH][2], dt[NH][2], z[NH][2];
#pragma unroll
      for (int h = 0; h < NH; ++h)
#pragma unroll
        for (int j2 = 0; j2 < 2; ++j2) { u[h][j2] = (f32x4){0.f,0.f,0.f,0.f}; dt[h][j2] = (f32x4){0.f,0.f,0.f,0.f}; z[h][j2] = (f32x4){0.f,0.f,0.f,0.f}; }
#pragma unroll
      for (int ss = 0; ss < 4; ++ss) {
        const int c0 = 32 * ss + g * 8;
        const s16x8 bW0 = *(const s16x8*)&Wib[o0 * 128 + c0];
        const s16x8 bW1 = *(const s16x8*)&Wib[o1 * 128 + c0];
        const s16x8 bD0 = *(const s16x8*)&Widb[o0 * 128 + c0];
        const s16x8 bD1 = *(const s16x8*)&Widb[o1 * 128 + c0];
#pragma unroll
        for (int h = 0; h < NH; ++h) {
          s16x8 av = *(const s16x8*)&bufA[(h * 16 + lm) * AST + c0];
          u[h][0]  = MFMA(av, bW0, u[h][0]);
          u[h][1]  = MFMA(av, bW1, u[h][1]);
          dt[h][0] = MFMA(av, bD0, dt[h][0]);
          dt[h][1] = MFMA(av, bD1, dt[h][1]);
        }
      }
#pragma unroll
      for (int ss = 0; ss < 2; ++ss) {
        const int c0 = 32 * ss + g * 8;
        const s16x8 bZ0 = *(const s16x8*)&Wzb[o0 * 64 + c0];
        const s16x8 bZ1 = *(const s16x8*)&Wzb[o1 * 64 + c0];
#pragma unroll
        for (int h = 0; h < NH; ++h) {
          s16x8 gv2 = *(const s16x8*)&bufB[(h * 16 + lm) * GSTB + c0];
          z[h][0] = MFMA(gv2, bZ0, z[h][0]);
          z[h][1] = MFMA(gv2, bZ1, z[h][1]);
        }
      }
#pragma unroll
      for (int h = 0; h < NH; ++h)
#pragma unroll
        for (int j2 = 0; j2 < 2; ++j2)
#pragma unroll
          for (int r = 0; r < 4; ++r) z[h][j2][r] = fast_silu(z[h][j2][r]);

      // scan: per channel-group, halves in order; carry chains in-wave
#pragma unroll
      for (int j2 = 0; j2 < 2; ++j2) {
        const int oc = j2 ? o1 : o0;
        const float bb = bb_s[d * CC + oc], na = na_s[d * CC + oc];
        float hcar = hs[d * CC + oc];
#pragma unroll
        for (int h = 0; h < NH; ++h) {
          float Pl[4], Dl[4]; float P = 0.f, D = 1.f;
#pragma unroll
          for (int r = 0; r < 4; ++r) {
            const float x = dt[h][j2][r] + bb;
            float dlt = fmaxf(x, 0.f) + __logf(1.f + __expf(-fabsf(x)));
            float dec = __expf(dlt * na), xin = dlt * u[h][j2][r];
            if (h * 16 + 4 * g + r >= tlen) { dec = 1.f; xin = 0.f; }
            P = dec * P + xin; D *= dec; Pl[r] = P; Dl[r] = D;
          }
          float Pi = P, Di = D;
          { float pa = __shfl_up(Pi, 16), da = __shfl_up(Di, 16);
            if (g >= 1) { Pi = Di * pa + Pi; Di *= da; }
            pa = __shfl_up(Pi, 32); da = __shfl_up(Di, 32);
            if (g >= 2) { Pi = Di * pa + Pi; Di *= da; } }
          float Pe = __shfl_up(Pi, 16), De = __shfl_up(Di, 16);
          if (g == 0) { Pe = 0.f; De = 1.f; }
          const float cr = De * hcar + Pe;
          const float Pf = __shfl(Pi, 48 + lm), Df = __shfl(Di, 48 + lm);
#pragma unroll
          for (int r = 0; r < 4; ++r) z[h][j2][r] = (Dl[r] * cr + Pl[r]) * z[h][j2][r];  // now y
          hcar = Df * hcar + Pf;
        }
        if (g == 0) hs[d * CC + oc] = hcar;
      }
      __syncthreads();   // all A-frag reads of bufA/bufB complete
#pragma unroll
      for (int h = 0; h < NH; ++h)
#pragma unroll
        for (int r = 0; r < 4; ++r) {
          const int rw = h * 16 + 4 * g + r;
          bufA[rw * AST + o0] = f2bf(z[h][0][r]);
          bufA[rw * AST + o1] = f2bf(z[h][1][r]);
        }
      __syncthreads();   // y visible
      // overlapped register gather of next tile (loads hide under GEMM2 + d1)
      if (d == 0 && t + 1 < nt) gather_tile();
      // m += y @ Wo ; g += silu(y @ Wyg)  (ss-outer B-frag reuse)
      f32x4 dm[NH][2], dgv[NH];
#pragma unroll
      for (int h = 0; h < NH; ++h) { dm[h][0] = (f32x4){0.f,0.f,0.f,0.f}; dm[h][1] = (f32x4){0.f,0.f,0.f,0.f}; dgv[h] = (f32x4){0.f,0.f,0.f,0.f}; }
#pragma unroll
      for (int ss = 0; ss < 4; ++ss) {
        const int c0 = 32 * ss + g * 8;
        const s16x8 bO0 = *(const s16x8*)&Wob[o0 * 128 + c0];
        const s16x8 bO1 = *(const s16x8*)&Wob[o1 * 128 + c0];
        const s16x8 bY  = *(const s16x8*)&Wyb[og * 128 + c0];
#pragma unroll
        for (int h = 0; h < NH; ++h) {
          s16x8 av = *(const s16x8*)&bufA[(h * 16 + lm) * AST + c0];
          dm[h][0] = MFMA(av, bO0, dm[h][0]);
          dm[h][1] = MFMA(av, bO1, dm[h][1]);
          dgv[h]   = MFMA(av, bY, dgv[h]);
        }
      }
      if (d == 0) {
        // residual update to LDS (input for d=1)
#pragma unroll
        for (int h = 0; h < NH; ++h)
#pragma unroll
          for (int r = 0; r < 4; ++r) {
            const int rw = h * 16 + 4 * g + r;
            mres[rw * AST + o0] = f2bf(b2f(mres[rw * AST + o0]) + dm[h][0][r]);
            mres[rw * AST + o1] = f2bf(b2f(mres[rw * AST + o1]) + dm[h][1][r]);
            gres[rw * GSTB + og] = f2bf(b2f(gres[rw * GSTB + og]) + fast_silu(dgv[h][r]));
          }
      } else {
        // d=1: final residual stays in registers -> packed f16 atomics, no barrier.
        const bool evn = (lm & 1) == 0;
#pragma unroll
        for (int h = 0; h < NH; ++h)
#pragma unroll
          for (int r = 0; r < 4; ++r) {
            const int rw = h * 16 + 4 * g + r;
            const float w = sc_w[cur][rw];
            const int tgt = sc_i[cur][rw];
            const float vm0 = (b2f(mres[rw * AST + o0]) + dm[h][0][r]) * w;
            const float vm1 = (b2f(mres[rw * AST + o1]) + dm[h][1][r]) * w;
            const float vg  = (b2f(gres[rw * GSTB + og]) + fast_silu(dgv[h][r])) * w;
            const float pm0 = __shfl_xor(vm0, 1);
            const float pm1 = __shfl_xor(vm1, 1);
            const float pg  = __shfl_xor(vg, 1);
            if (w != 0.f) {
              if (evn) {
                atomic_pk2(accm_h + tgt * CC + o0, vm0, pm0);
                atomic_pk2(accg_h + tgt * GG + og, vg, pg);
              } else {
                atomic_pk2(accm_h + tgt * CC + o1 - 1, pm1, vm1);
              }
            }
          }
      }
    }
    cur = nxt;   // atomics drain at next loop-top barrier, overlapped
  }
}

extern "C" void kernel_launch(void* const* d_in, const int* in_sizes, int n_in,
                              void* d_out, int out_size, void* d_ws, size_t ws_size,
                              hipStream_t stream) {
  (void)in_sizes; (void)n_in; (void)out_size; (void)ws_size;
  float* ws = (float*)d_ws;
  KArgs a;
  a.fm[0]  = (const float*)d_in[0]; a.fm[1]  = (const float*)d_in[1];
  a.fg[0]  = (const float*)d_in[2]; a.fg[1]  = (const float*)d_in[3];
  a.flow[0] = (const float*)d_in[4]; a.flow[1] = (const float*)d_in[5];
  a.sx[0] = (const float*)d_in[6]; a.sy[0] = (const float*)d_in[7];
  a.sx[1] = (const float*)d_in[8]; a.sy[1] = (const float*)d_in[9];
  a.Wi  = (const float*)d_in[10]; a.Wz   = (const float*)d_in[11];
  a.Wdt = (const float*)d_in[12]; a.bdt  = (const float*)d_in[13];
  a.alog = (const float*)d_in[14]; a.Wo  = (const float*)d_in[15];
  a.Wyg = (const float*)d_in[16];
  a.fmT[0] = ws + OFF_FMT0; a.fmT[1] = ws + OFF_FMT1;
  a.fgT[0] = ws + OFF_FGT0; a.fgT[1] = ws + OFF_FGT1;
  a.accm[0] = ws + OFF_ACCM0; a.accm[1] = ws + OFF_ACCM1;
  a.accg[0] = ws + OFF_ACCG0; a.accg[1] = ws + OFF_ACCG1;
  a.accw[0] = ws + OFF_ACCW0; a.accw[1] = ws + OFF_ACCW1;
  a.cnt  = (int*)(ws + OFF_CNT);
  a.cnt2 = (int*)(ws + OFF_CNT2);
  a.job  = (int*)(ws + OFF_JOB);
  a.wb   = (unsigned short*)(ws + OFF_WB);
  a.out = (float*)d_out;

  k_zero<<<1183, 256, 0, stream>>>(ws + OFF_ACCM0, ACC_FLOATS);
  k_zero<<<1, 256, 0, stream>>>(ws + OFF_CNT, 48);
  k_prep<<<1176, 256, 0, stream>>>(a);
  k_prepw<<<1536, 256, 0, stream>>>(a);
  k_prepwid<<<dim3(6, 128), 128, 0, stream>>>(a);
  k_count<<<7, 256, 0, stream>>>(a);
  k_assign<<<7, 256, 0, stream>>>(a);
  k_main<<<1568, 256, 0, stream>>>(a);
  k_fin<<<1176, 256, 0, stream>>>(a);
}

// Round 17
// 199.508 us; speedup vs baseline: 1.2936x; 1.2936x over previous
//
#include <hip/hip_runtime.h>
#include <math.h>

typedef short s16x8 __attribute__((ext_vector_type(8)));
typedef unsigned short u16x8v __attribute__((ext_vector_type(8)));
typedef float f32x4 __attribute__((ext_vector_type(4)));
typedef _Float16 h2 __attribute__((ext_vector_type(2)));

#define HH 28
#define WW 28
#define PP 784
#define CC 128
#define GG 64
#define MT 48     // macro-tile tokens (3 halves of 16)
#define NH 3
#define AST 136   // bf16 row stride for 128-ch buffers
#define GSTB 72   // bf16 row stride for 64-ch buffers

// ---- workspace layout (float-slot offsets); acc regions hold f16 ----
#define OFF_FMT0 0
#define OFF_FMT1 100352
#define OFF_FGT0 200704
#define OFF_FGT1 250880
#define OFF_ACCM0 301056
#define OFF_ACCM1 401408
#define OFF_ACCG0 501760
#define OFF_ACCG1 551936
#define OFF_ACCW0 602112
#define OFF_ACCW1 602896
#define ACC_FLOATS 302624   // accm0..accw1 (zeroing range; f32 zeros = f16 zero pairs)
#define OFF_CNT   603680    // 24 ints  (region*3+group)
#define OFF_CNT2  603704    // 24 ints
#define OFF_JOB   603728    // 1568 ints -> ends 605296
#define OFF_WB    605296    // bf16 weights, 393216 ushorts -> ends 801904

// bf16 weight sub-offsets (ushort units), layout [set=(si*2+d)][out][in]
#define WIB 0        // Wi^T
#define WZB 98304    // Wz^T
#define WDB 147456   // Wid = (Wi@Wdt)^T  (composite)
#define WOB 245760   // Wo^T
#define WYB 344064   // Wyg^T

struct KArgs {
  const float* fm[2]; const float* fg[2];
  const float* flow[2]; const float* sx[2]; const float* sy[2];
  const float* Wi; const float* Wz; const float* Wdt; const float* bdt;
  const float* alog; const float* Wo; const float* Wyg;
  float* fmT[2]; float* fgT[2];
  float* accm[2]; float* accg[2]; float* accw[2];   // accm/accg interpreted as f16
  int* cnt; int* cnt2; int* job;
  unsigned short* wb;
  float* out;
};

__device__ __forceinline__ int span_group(float avg, int& s) {
  if (fabsf(avg - 15.f) < 1.5f) { s = 15; return 0; }
  if (fabsf(avg - 9.f)  < 1.5f) { s = 9;  return 1; }
  if (fabsf(avg - 5.f)  < 1.5f) { s = 5;  return 2; }
  s = 0; return 3;
}

__device__ __forceinline__ float fast_silu(float x) {
  return x * __builtin_amdgcn_rcpf(1.f + __expf(-x));
}

__device__ __forceinline__ unsigned short f2bf(float f) {
  unsigned u = __float_as_uint(f);
  unsigned r = (u + 0x7fffu + ((u >> 16) & 1u)) >> 16;
  return (unsigned short)r;
}
__device__ __forceinline__ float b2f(unsigned short u) {
  return __uint_as_float(((unsigned)u) << 16);
}

// packed 2xf16 atomic add (HW global_atomic_pk_add_f16; CAS fallback)
__device__ __forceinline__ void atomic_pk2(_Float16* base, float x, float y) {
  h2 v; v[0] = (_Float16)x; v[1] = (_Float16)y;
#if __has_builtin(__builtin_amdgcn_global_atomic_fadd_v2f16)
  __builtin_amdgcn_global_atomic_fadd_v2f16((h2*)base, v);
#else
  unsigned* a = (unsigned*)base;
  unsigned old = *a, assumed;
  do {
    assumed = old;
    h2 cur = *(h2*)&assumed;
    h2 nw; nw[0] = cur[0] + v[0]; nw[1] = cur[1] + v[1];
    old = atomicCAS(a, assumed, *(unsigned*)&nw);
  } while (old != assumed);
#endif
}

#define MFMA(A_, B_, C_) __builtin_amdgcn_mfma_f32_16x16x32_bf16((A_), (B_), (C_), 0, 0, 0)

__global__ void k_zero(float* p, int n) {
  int j = blockIdx.x * 256 + threadIdx.x;
  if (j < n) p[j] = 0.f;
}

// transpose features to [pos][ch], f32
__global__ void k_prep(KArgs a) {
  int j = blockIdx.x * 256 + threadIdx.x;     // 301056 exactly
  int side = j / 150528; int r = j - side * 150528;
  int p = r / 192; int ch = r - p * 192;
  if (ch < CC) a.fmT[side][p * CC + ch] = a.fm[side][ch * PP + p];
  else         a.fgT[side][p * GG + (ch - CC)] = a.fg[side][(ch - CC) * PP + p];
}

// transpose + bf16-convert weights to [set][out][in]; WDB written by k_prepwid
__global__ void k_prepw(KArgs a) {
  int j = blockIdx.x * 256 + threadIdx.x;     // 393216 exactly
  unsigned short* wb = a.wb;
  if (j < 98304) {
    int set = j >> 14, r = j & 16383; int o = r >> 7, c = r & 127;
    wb[WIB + j] = f2bf(a.Wi[set * 16384 + c * 128 + o]);
  } else if (j < 147456) {
    int r = j - 98304; int set = r >> 13, rr = r & 8191; int o = rr >> 6, c = rr & 63;
    wb[WZB + r] = f2bf(a.Wz[set * 8192 + c * 128 + o]);
  } else if (j < 245760) {
    // WDB region: written by k_prepwid
  } else if (j < 344064) {
    int r = j - 245760; int set = r >> 14, rr = r & 16383; int o = rr >> 7, c = rr & 127;
    wb[WOB + r] = f2bf(a.Wo[set * 16384 + c * 128 + o]);
  } else {
    int r = j - 344064; int set = r >> 13, rr = r & 8191; int o = rr >> 7, c = rr & 127;
    wb[WYB + r] = f2bf(a.Wyg[set * 8192 + c * 64 + o]);
  }
}

// composite Wid[set][o][i] = sum_m Wi[set][i][m] * Wdt[set][m][o]
__global__ void k_prepwid(KArgs a) {
  __shared__ float wi_row[128];
  const int set = blockIdx.x, i = blockIdx.y, o = threadIdx.x;
  wi_row[o] = a.Wi[set * 16384 + i * 128 + o];
  __syncthreads();
  float acc = 0.f;
#pragma unroll 4
  for (int m = 0; m < 128; ++m) acc = fmaf(wi_row[m], a.Wdt[set * 16384 + m * 128 + o], acc);
  a.wb[WDB + set * 16384 + o * 128 + i] = f2bf(acc);
}

// per-(region,group) counts; also reset job slots to -1
__global__ void k_count(KArgs a) {
  int j = blockIdx.x * 256 + threadIdx.x;
  if (j >= 2 * PP) return;
  a.job[j] = -1;
  int side = j / PP, p = j - side * PP;
  float avg = 0.5f * (a.sx[side][p] + a.sy[side][p]);
  int s; int g = span_group(avg, s);
  if (g < 3) {
    int py = p / WW, px = p - py * WW;
    int region = (py / 14) * 4 + px / 7;
    atomicAdd(&a.cnt[region * 3 + g], 1);
  }
}

// XCD-clustered slots: slot = region + 8*rank; span-15 gets low ranks.
__global__ void k_assign(KArgs a) {
  int j = blockIdx.x * 256 + threadIdx.x;
  if (j >= 2 * PP) return;
  int side = j / PP, p = j - side * PP;
  float avg = 0.5f * (a.sx[side][p] + a.sy[side][p]);
  int s; int g = span_group(avg, s);
  if (g < 3) {
    int py = p / WW, px = p - py * WW;
    int region = (py / 14) * 4 + px / 7;
    int base = 0;
    for (int gg = 0; gg < g; ++gg) base += a.cnt[region * 3 + gg];
    int rank = base + atomicAdd(&a.cnt2[region * 3 + g], 1);
    a.job[region + 8 * rank] = (side << 10) | p;   // rank <= 195 -> slot <= 1567
  }
}

__global__ void k_fin(KArgs a) {
  int j = blockIdx.x * 256 + threadIdx.x;     // 301056 exactly
  int side = j / 150528; int r = j - side * 150528;
  int p = r / 192; int ch = r - p * 192;
  float inv = 1.f / fmaxf(a.accw[side][p], 1e-6f);
  if (ch < CC) {
    const _Float16* amh = (const _Float16*)a.accm[side];
    a.out[side * 100352 + ch * PP + p] = (float)amh[p * CC + ch] * inv;
  } else {
    const _Float16* agh = (const _Float16*)a.accg[side];
    a.out[200704 + side * 50176 + (ch - CC) * PP + p] = (float)agh[p * GG + (ch - CC)] * inv;
  }
}

__launch_bounds__(256, 3)
__global__ void k_main(KArgs a) {
  __shared__ __align__(16) unsigned short mres[MT * AST];   // bf16 m residual (single)
  __shared__ __align__(16) unsigned short gres[MT * GSTB];  // bf16 g residual (single)
  __shared__ __align__(16) unsigned short bufA[MT * AST];   // xnorm_m, then y
  __shared__ __align__(16) unsigned short bufB[MT * GSTB];  // gnorm
  __shared__ float hs[2 * CC];
  __shared__ float na_s[2 * CC];
  __shared__ float bb_s[2 * CC];
  __shared__ float pw_l[228];
  __shared__ int   tap_i[MT * 4];
  __shared__ float tap_w[MT * 4];
  __shared__ int   sc_i[MT];
  __shared__ float sc_w[MT];
  __shared__ float red[4];

  const int tid = threadIdx.x;
  const int job = a.job[blockIdx.x];
  if (job < 0) return;
  const int side = job >> 10, p = job & 1023;
  const float avg = 0.5f * (a.sx[side][p] + a.sy[side][p]);
  int s; const int si = span_group(avg, s);
  const int hspan = s >> 1, L = s * s;
  const int py = p / WW, px = p - py * WW;
  const float fdx = a.flow[side][p * 4 + 0], fdy = a.flow[side][p * 4 + 1];
  const float cy = fminf(fmaxf((float)py + fdy, 0.f), (float)(HH - 1));
  const float cx = fminf(fmaxf((float)px + fdx, 0.f), (float)(WW - 1));
  const float* fmT = a.fmT[side]; const float* fgT = a.fgT[side];
  _Float16* accm_h = (_Float16*)a.accm[side];
  _Float16* accg_h = (_Float16*)a.accg[side];
  float* accw = a.accw[side];

  const unsigned short* wb = a.wb;
  const int wv = tid >> 6, l = tid & 63, lm = l & 15, g = l >> 4;
  const int o0 = 32 * wv + lm, o1 = o0 + 16, og = 16 * wv + lm;
  const int ttk = tid >> 3, c8 = tid & 7;     // sampling decomposition (2 tokens/thread)

  { const int d2 = tid >> 7, c2 = tid & 127;
    na_s[tid] = -__expf(a.alog[(si * 2 + d2) * CC + c2]);
    bb_s[tid] = a.bdt[(si * 2 + d2) * CC + c2];
    hs[tid] = 0.f; }
  if (tid < L) {
    const int dyi = tid / s - hspan, dxi = tid % s - hspan;
    pw_l[tid] = __expf(-sqrtf((float)(dyi * dyi + dxi * dxi)) / (0.5f * (float)s));
  }
  __syncthreads();
  { float v = (tid < L) ? pw_l[tid] : 0.f;
#pragma unroll
    for (int off = 32; off > 0; off >>= 1) v += __shfl_xor(v, off);
    if ((tid & 63) == 0) red[tid >> 6] = v; }
  __syncthreads();
  { const float pinv = 1.f / (red[0] + red[1] + red[2] + red[3]);
    if (tid < L) pw_l[tid] *= pinv; }
  __syncthreads();

  const int nt = (L + MT - 1) / MT;

  for (int t = 0; t < nt; ++t) {
    const int t0 = t * MT;
    const int tlen = min(MT, L - t0);
    // taps + scatter targets for this tile (all MT slots written)
    if (tid < MT) {
      const int t2 = t0 + tid;
      if (t2 < L) {
        const int tq = t2 / s;
        const int dyi = tq - hspan, dxi = (t2 - tq * s) - hspan;
        const float ys = cy + (float)dyi, xs = cx + (float)dxi;
        const float y0f = floorf(ys), x0f = floorf(xs);
        const float wy = ys - y0f, wx = xs - x0f;
        const int y0 = (int)y0f, x0 = (int)x0f;
#pragma unroll
        for (int k = 0; k < 4; ++k) {
          const int yi = y0 + (k >> 1), xi = x0 + (k & 1);
          const bool v = (yi >= 0) && (yi < HH) && (xi >= 0) && (xi < WW);
          const int yc = min(max(yi, 0), HH - 1), xc = min(max(xi, 0), WW - 1);
          tap_i[tid * 4 + k] = yc * WW + xc;
          const float wgt = ((k >> 1) ? wy : 1.f - wy) * ((k & 1) ? wx : 1.f - wx);
          tap_w[tid * 4 + k] = v ? wgt : 0.f;
        }
        const int ty = py + dyi, tx = px + dxi;
        const bool sv = (ty >= 0) && (ty < HH) && (tx >= 0) && (tx < WW);
        const int sid2 = sv ? ty * WW + tx : 0;
        const float sw = sv ? pw_l[t2] : 0.f;
        sc_i[tid] = sid2; sc_w[tid] = sw;
        if (sw != 0.f) atomicAdd(&accw[sid2], sw);
      } else {
#pragma unroll
        for (int k = 0; k < 4; ++k) { tap_i[tid * 4 + k] = 0; tap_w[tid * 4 + k] = 0.f; }
        sc_i[tid] = 0; sc_w[tid] = 0.f;
      }
    }
    __syncthreads();   // taps visible (and prev-tile residual readers done)
    // straight-line vectorized sampling, direct to LDS (no registers held):
    // thread covers tokens {ttk, ttk+32} x 16 m-ch + 8 g-ch, 24 float4 loads each
    for (int tk = ttk; tk < MT; tk += 32) {
      const int* ti = &tap_i[tk * 4]; const float* tw = &tap_w[tk * 4];
      f32x4 am0 = {0.f,0.f,0.f,0.f}, am1 = am0, am2 = am0, am3 = am0;
      f32x4 ag0 = am0, ag1 = am0;
#pragma unroll
      for (int k2 = 0; k2 < 4; ++k2) {
        const float w = tw[k2];
        const float* pm = &fmT[ti[k2] * CC + c8 * 16];
        am0 += w * *(const f32x4*)&pm[0];
        am1 += w * *(const f32x4*)&pm[4];
        am2 += w * *(const f32x4*)&pm[8];
        am3 += w * *(const f32x4*)&pm[12];
        const float* pg = &fgT[ti[k2] * GG + c8 * 8];
        ag0 += w * *(const f32x4*)&pg[0];
        ag1 += w * *(const f32x4*)&pg[4];
      }
      u16x8v w0, w1, wg;
#pragma unroll
      for (int j = 0; j < 4; ++j) {
        w0[j] = f2bf(am0[j]); w0[4 + j] = f2bf(am1[j]);
        w1[j] = f2bf(am2[j]); w1[4 + j] = f2bf(am3[j]);
        wg[j] = f2bf(ag0[j]); wg[4 + j] = f2bf(ag1[j]);
      }
      *(u16x8v*)&mres[tk * AST + c8 * 16] = w0;
      *(u16x8v*)&mres[tk * AST + c8 * 16 + 8] = w1;
      *(u16x8v*)&gres[tk * GSTB + c8 * 8] = wg;
    }
    // no barrier needed: rmsnorm below reads the same (tk,c8) slots this thread wrote

    for (int d = 0; d < 2; ++d) {
      const unsigned short* Wib  = wb + WIB + (si * 2 + d) * 16384;
      const unsigned short* Widb = wb + WDB + (si * 2 + d) * 16384;
      const unsigned short* Wzb  = wb + WZB + (si * 2 + d) * 8192;
      const unsigned short* Wob  = wb + WOB + (si * 2 + d) * 16384;
      const unsigned short* Wyb  = wb + WYB + (si * 2 + d) * 8192;
      if (d == 1) __syncthreads();   // d0 residual updates visible
      // rmsnorm: thread covers tokens {ttk, ttk+32}, 8 lanes/token
      for (int tk = ttk; tk < MT; tk += 32) {
        u16x8v m0 = *(const u16x8v*)&mres[tk * AST + c8 * 16];
        u16x8v m1 = *(const u16x8v*)&mres[tk * AST + c8 * 16 + 8];
        u16x8v gv = *(const u16x8v*)&gres[tk * GSTB + c8 * 8];
        float mv[16], gvf[8];
#pragma unroll
        for (int k = 0; k < 8; ++k) { mv[k] = b2f(m0[k]); mv[8 + k] = b2f(m1[k]); gvf[k] = b2f(gv[k]); }
        float ssm = 0.f, ssg = 0.f;
#pragma unroll
        for (int k = 0; k < 16; ++k) ssm = fmaf(mv[k], mv[k], ssm);
#pragma unroll
        for (int k = 0; k < 8; ++k) ssg = fmaf(gvf[k], gvf[k], ssg);
#pragma unroll
        for (int off = 4; off > 0; off >>= 1) { ssm += __shfl_xor(ssm, off); ssg += __shfl_xor(ssg, off); }
        const float sm = rsqrtf(ssm * (1.f / CC) + 1e-5f);
        const float sgs = rsqrtf(ssg * (1.f / GG) + 1e-5f);
        u16x8v xa, xb, gx;
#pragma unroll
        for (int k = 0; k < 8; ++k) { xa[k] = f2bf(mv[k] * sm); xb[k] = f2bf(mv[8 + k] * sm); gx[k] = f2bf(gvf[k] * sgs); }
        *(u16x8v*)&bufA[tk * AST + c8 * 16] = xa;
        *(u16x8v*)&bufA[tk * AST + c8 * 16 + 8] = xb;
        *(u16x8v*)&bufB[tk * GSTB + c8 * 8] = gx;
      }
      __syncthreads();   // xnorm/gnorm visible
      // u = x@Wi ; delta_pre = x@Wid ; z = silu(g@Wz)  (ss-outer B-frag reuse)
      f32x4 u[NH][2], dt[NH][2], z[NH][2];
#pragma unroll
      for (int h = 0; h < NH; ++h)
#pragma unroll
        for (int j2 = 0; j2 < 2; ++j2) { u[h][j2] = (f32x4){0.f,0.f,0.f,0.f}; dt[h][j2] = (f32x4){0.f,0.f,0.f,0.f}; z[h][j2] = (f32x4){0.f,0.f,0.f,0.f}; }
#pragma unroll
      for (int ss = 0; ss < 4; ++ss) {
        const int c0 = 32 * ss + g * 8;
        const s16x8 bW0 = *(const s16x8*)&Wib[o0 * 128 + c0];
        const s16x8 bW1 = *(const s16x8*)&Wib[o1 * 128 + c0];
        const s16x8 bD0 = *(const s16x8*)&Widb[o0 * 128 + c0];
        const s16x8 bD1 = *(const s16x8*)&Widb[o1 * 128 + c0];
#pragma unroll
        for (int h = 0; h < NH; ++h) {
          s16x8 av = *(const s16x8*)&bufA[(h * 16 + lm) * AST + c0];
          u[h][0]  = MFMA(av, bW0, u[h][0]);
          u[h][1]  = MFMA(av, bW1, u[h][1]);
          dt[h][0] = MFMA(av, bD0, dt[h][0]);
          dt[h][1] = MFMA(av, bD1, dt[h][1]);
        }
      }
#pragma unroll
      for (int ss = 0; ss < 2; ++ss) {
        const int c0 = 32 * ss + g * 8;
        const s16x8 bZ0 = *(const s16x8*)&Wzb[o0 * 64 + c0];
        const s16x8 bZ1 = *(const s16x8*)&Wzb[o1 * 64 + c0];
#pragma unroll
        for (int h = 0; h < NH; ++h) {
          s16x8 gv2 = *(const s16x8*)&bufB[(h * 16 + lm) * GSTB + c0];
          z[h][0] = MFMA(gv2, bZ0, z[h][0]);
          z[h][1] = MFMA(gv2, bZ1, z[h][1]);
        }
      }
#pragma unroll
      for (int h = 0; h < NH; ++h)
#pragma unroll
        for (int j2 = 0; j2 < 2; ++j2)
#pragma unroll
          for (int r = 0; r < 4; ++r) z[h][j2][r] = fast_silu(z[h][j2][r]);

      // scan: per channel-group, halves in order; carry chains in-wave
#pragma unroll
      for (int j2 = 0; j2 < 2; ++j2) {
        const int oc = j2 ? o1 : o0;
        const float bb = bb_s[d * CC + oc], na = na_s[d * CC + oc];
        float hcar = hs[d * CC + oc];
#pragma unroll
        for (int h = 0; h < NH; ++h) {
          float Pl[4], Dl[4]; float P = 0.f, D = 1.f;
#pragma unroll
          for (int r = 0; r < 4; ++r) {
            const float x = dt[h][j2][r] + bb;
            float dlt = fmaxf(x, 0.f) + __logf(1.f + __expf(-fabsf(x)));
            float dec = __expf(dlt * na), xin = dlt * u[h][j2][r];
            if (h * 16 + 4 * g + r >= tlen) { dec = 1.f; xin = 0.f; }
            P = dec * P + xin; D *= dec; Pl[r] = P; Dl[r] = D;
          }
          float Pi = P, Di = D;
          { float pa = __shfl_up(Pi, 16), da = __shfl_up(Di, 16);
            if (g >= 1) { Pi = Di * pa + Pi; Di *= da; }
            pa = __shfl_up(Pi, 32); da = __shfl_up(Di, 32);
            if (g >= 2) { Pi = Di * pa + Pi; Di *= da; } }
          float Pe = __shfl_up(Pi, 16), De = __shfl_up(Di, 16);
          if (g == 0) { Pe = 0.f; De = 1.f; }
          const float cr = De * hcar + Pe;
          const float Pf = __shfl(Pi, 48 + lm), Df = __shfl(Di, 48 + lm);
#pragma unroll
          for (int r = 0; r < 4; ++r) z[h][j2][r] = (Dl[r] * cr + Pl[r]) * z[h][j2][r];  // now y
          hcar = Df * hcar + Pf;
        }
        if (g == 0) hs[d * CC + oc] = hcar;
      }
      __syncthreads();   // all A-frag reads of bufA/bufB complete
#pragma unroll
      for (int h = 0; h < NH; ++h)
#pragma unroll
        for (int r = 0; r < 4; ++r) {
          const int rw = h * 16 + 4 * g + r;
          bufA[rw * AST + o0] = f2bf(z[h][0][r]);
          bufA[rw * AST + o1] = f2bf(z[h][1][r]);
        }
      __syncthreads();   // y visible
      // m += y @ Wo ; g += silu(y @ Wyg)  (ss-outer B-frag reuse)
      f32x4 dm[NH][2], dgv[NH];
#pragma unroll
      for (int h = 0; h < NH; ++h) { dm[h][0] = (f32x4){0.f,0.f,0.f,0.f}; dm[h][1] = (f32x4){0.f,0.f,0.f,0.f}; dgv[h] = (f32x4){0.f,0.f,0.f,0.f}; }
#pragma unroll
      for (int ss = 0; ss < 4; ++ss) {
        const int c0 = 32 * ss + g * 8;
        const s16x8 bO0 = *(const s16x8*)&Wob[o0 * 128 + c0];
        const s16x8 bO1 = *(const s16x8*)&Wob[o1 * 128 + c0];
        const s16x8 bY  = *(const s16x8*)&Wyb[og * 128 + c0];
#pragma unroll
        for (int h = 0; h < NH; ++h) {
          s16x8 av = *(const s16x8*)&bufA[(h * 16 + lm) * AST + c0];
          dm[h][0] = MFMA(av, bO0, dm[h][0]);
          dm[h][1] = MFMA(av, bO1, dm[h][1]);
          dgv[h]   = MFMA(av, bY, dgv[h]);
        }
      }
      if (d == 0) {
        // residual update to LDS (input for d=1)
#pragma unroll
        for (int h = 0; h < NH; ++h)
#pragma unroll
          for (int r = 0; r < 4; ++r) {
            const int rw = h * 16 + 4 * g + r;
            mres[rw * AST + o0] = f2bf(b2f(mres[rw * AST + o0]) + dm[h][0][r]);
            mres[rw * AST + o1] = f2bf(b2f(mres[rw * AST + o1]) + dm[h][1][r]);
            gres[rw * GSTB + og] = f2bf(b2f(gres[rw * GSTB + og]) + fast_silu(dgv[h][r]));
          }
      } else {
        // d=1: final residual stays in registers -> packed f16 atomics, no barrier.
        const bool evn = (lm & 1) == 0;
#pragma unroll
        for (int h = 0; h < NH; ++h)
#pragma unroll
          for (int r = 0; r < 4; ++r) {
            const int rw = h * 16 + 4 * g + r;
            const float w = sc_w[rw];
            const int tgt = sc_i[rw];
            const float vm0 = (b2f(mres[rw * AST + o0]) + dm[h][0][r]) * w;
            const float vm1 = (b2f(mres[rw * AST + o1]) + dm[h][1][r]) * w;
            const float vg  = (b2f(gres[rw * GSTB + og]) + fast_silu(dgv[h][r])) * w;
            const float pm0 = __shfl_xor(vm0, 1);
            const float pm1 = __shfl_xor(vm1, 1);
            const float pg  = __shfl_xor(vg, 1);
            if (w != 0.f) {
              if (evn) {
                atomic_pk2(accm_h + tgt * CC + o0, vm0, pm0);
                atomic_pk2(accg_h + tgt * GG + og, vg, pg);
              } else {
                atomic_pk2(accm_h + tgt * CC + o1 - 1, pm1, vm1);
              }
            }
          }
      }
    }
    __syncthreads();   // protect sc/taps/residual tiles before next tile
  }
}

extern "C" void kernel_launch(void* const* d_in, const int* in_sizes, int n_in,
                              void* d_out, int out_size, void* d_ws, size_t ws_size,
                              hipStream_t stream) {
  (void)in_sizes; (void)n_in; (void)out_size; (void)ws_size;
  float* ws = (float*)d_ws;
  KArgs a;
  a.fm[0]  = (const float*)d_in[0]; a.fm[1]  = (const float*)d_in[1];
  a.fg[0]  = (const float*)d_in[2]; a.fg[1]  = (const float*)d_in[3];
  a.flow[0] = (const float*)d_in[4]; a.flow[1] = (const float*)d_in[5];
  a.sx[0] = (const float*)d_in[6]; a.sy[0] = (const float*)d_in[7];
  a.sx[1] = (const float*)d_in[8]; a.sy[1] = (const float*)d_in[9];
  a.Wi  = (const float*)d_in[10]; a.Wz   = (const float*)d_in[11];
  a.Wdt = (const float*)d_in[12]; a.bdt  = (const float*)d_in[13];
  a.alog = (const float*)d_in[14]; a.Wo  = (const float*)d_in[15];
  a.Wyg = (const float*)d_in[16];
  a.fmT[0] = ws + OFF_FMT0; a.fmT[1] = ws + OFF_FMT1;
  a.fgT[0] = ws + OFF_FGT0; a.fgT[1] = ws + OFF_FGT1;
  a.accm[0] = ws + OFF_ACCM0; a.accm[1] = ws + OFF_ACCM1;
  a.accg[0] = ws + OFF_ACCG0; a.accg[1] = ws + OFF_ACCG1;
  a.accw[0] = ws + OFF_ACCW0; a.accw[1] = ws + OFF_ACCW1;
  a.cnt  = (int*)(ws + OFF_CNT);
  a.cnt2 = (int*)(ws + OFF_CNT2);
  a.job  = (int*)(ws + OFF_JOB);
  a.wb   = (unsigned short*)(ws + OFF_WB);
  a.out = (float*)d_out;

  k_zero<<<1183, 256, 0, stream>>>(ws + OFF_ACCM0, ACC_FLOATS);
  k_zero<<<1, 256, 0, stream>>>(ws + OFF_CNT, 48);
  k_prep<<<1176, 256, 0, stream>>>(a);
  k_prepw<<<1536, 256, 0, stream>>>(a);
  k_prepwid<<<dim3(6, 128), 128, 0, stream>>>(a);
  k_count<<<7, 256, 0, stream>>>(a);
  k_assign<<<7, 256, 0, stream>>>(a);
  k_main<<<1568, 256, 0, stream>>>(a);
  k_fin<<<1176, 256, 0, stream>>>(a);
}